// Round 6
// baseline (314.791 us; speedup 1.0000x reference)
//
#include <hip/hip_runtime.h>
#include <hip/hip_bf16.h>

// AttentionPoolingAdvance: B=8,S=2048,D=768 (fp32 in/out, detected on device).
// out[b] = mean_q softmax((Q K^T)/sqrt(D), key-mask) V
// Algebra: out = (c^T x) Wv^T + bv with c_k=(1/S) sum_q w[q,k];
// score[q,k] == (z_q.x_k)/sqrt(D) + beta_k modulo softmax-invariant terms,
// z = x @ (Wq^T Wk), beta_k = x_k.(Wk^T bq)/sqrt(D); bk cancels.
// Round 13: pass1+pass2 fused -> score GEMM computed ONCE. nb<=4 so the
// score grid (<=256 blocks, 1 block/CU @128KB LDS) is fully co-resident;
// the 8 blocks sharing an m-tile sync through a device-scope counter
// (atomic l partials -> vmcnt0+threadfence -> cnt++ -> spin to 8 -> atomic
// l readback -> weight with still-live acc). Halves the score-GEMM FLOPs
// (was 66+62 us for two identical GEMMs).

#define S 2048
#define DIM 768
#define BATCH 8

typedef __hip_bfloat16 bf16;
typedef __attribute__((ext_vector_type(8))) short bf16x8;
typedef __attribute__((ext_vector_type(4))) short short4v;
typedef __attribute__((ext_vector_type(4))) float f32x4;

__device__ __forceinline__ f32x4 mfma16(bf16x8 a, bf16x8 b, f32x4 c) {
  return __builtin_amdgcn_mfma_f32_16x16x32_bf16(a, b, c, 0, 0, 0);
}

__device__ __forceinline__ void load_lds16(const short* g, short* l) {
  __builtin_amdgcn_global_load_lds(
      (const __attribute__((address_space(1))) unsigned int*)g,
      (__attribute__((address_space(3))) unsigned int*)l, 16, 0, 0);
}

__device__ __forceinline__ float b2f(short u) {
  union { float f; unsigned u; } v;
  v.u = ((unsigned)(unsigned short)u) << 16;
  return v.f;
}

__device__ __forceinline__ short f2b(float f) {
  bf16 h = __float2bfloat16(f);
  return *(short*)&h;
}

#define INV_SCALE 0.03608439182435161f  // 1/sqrt(768)

// ---- dtype probe: bf16 N(0,1) halfwords have exp field in ~[115,130];
// fp32 mantissa halfwords are ~uniform -> flagged out of [96,159). ----
__global__ __launch_bounds__(256) void detect_dtype(const unsigned short* __restrict__ x,
                                                    int* __restrict__ flag) {
  int bad = 0;
  for (int i = threadIdx.x; i < 2048; i += 256) {
    int e = (x[i] >> 7) & 0xFF;
    if (e < 0x60 || e >= 0x9F) bad = 1;
  }
  if (bad) atomicOr(flag, 1);  // 1 => fp32 inputs
}

// ---- prep: blocks 0..287 transpose Wq/Wk -> bf16 T; 288..293 bvec partials.
// bvec[j] = sum_o Wk[o,j]*bq[o]  (bvec pre-zeroed; atomic partial per chunk)
__global__ __launch_bounds__(256) void prep_kernel(const void* __restrict__ Wq_raw,
                                                   const void* __restrict__ Wk_raw,
                                                   const void* __restrict__ bq_raw,
                                                   bf16* __restrict__ T0,
                                                   bf16* __restrict__ T1,
                                                   float* __restrict__ bvec,
                                                   const int* __restrict__ flag) {
  const int f = *flag;
  const int bx = blockIdx.x;
  if (bx < 288) {
    __shared__ unsigned short tile[64][66];
    const int p = bx / 144, r = bx % 144;
    const void* src = p ? Wk_raw : Wq_raw;
    unsigned short* dst = (unsigned short*)(p ? T1 : T0);
    const int obase = (r / 12) * 64, ibase = (r % 12) * 64;
    const int col = threadIdx.x & 63, rq = threadIdx.x >> 6;
#pragma unroll
    for (int rr = 0; rr < 64; rr += 4) {
      const long idx = (long)(obase + rr + rq) * DIM + ibase + col;
      const float v = f ? ((const float*)src)[idx] : b2f(((const short*)src)[idx]);
      tile[rr + rq][col] = (unsigned short)f2b(v);
    }
    __syncthreads();
#pragma unroll
    for (int rr = 0; rr < 64; rr += 4)
      dst[(long)(ibase + rr + rq) * DIM + obase + col] = tile[col][rr + rq];
  } else {
    const int o0 = (bx - 288) * 128;
    const int t = threadIdx.x;
    float s0 = 0.f, s1 = 0.f, s2 = 0.f;
    if (f) {
      const float* W = (const float*)Wk_raw;
      const float* bq = (const float*)bq_raw;
      for (int o = o0; o < o0 + 128; ++o) {
        const float bo = bq[o];
        const float* row = W + (long)o * DIM;
        s0 += row[t] * bo;
        s1 += row[t + 256] * bo;
        s2 += row[t + 512] * bo;
      }
    } else {
      const short* W = (const short*)Wk_raw;
      const short* bq = (const short*)bq_raw;
      for (int o = o0; o < o0 + 128; ++o) {
        const float bo = b2f(bq[o]);
        const short* row = W + (long)o * DIM;
        s0 += b2f(row[t]) * bo;
        s1 += b2f(row[t + 256]) * bo;
        s2 += b2f(row[t + 512]) * bo;
      }
    }
    atomicAdd(&bvec[t], s0);
    atomicAdd(&bvec[t + 256], s1);
    atomicAdd(&bvec[t + 512], s2);
  }
}

// ================= m97-style tiled NT GEMM core (kept for mt_convert) ======
// 128x128 C-tile per 256-thread block (4 waves, 2x2), BK=32, K=768,
// A,B row-major ld=768. Staging via global_load_lds width 16.
#define TILE_DECLS                                                          \
  __shared__ short As[4096], Bs[4096];                                      \
  const int tid = threadIdx.x;                                              \
  const int wave = tid >> 6, lane = tid & 63;                               \
  const int lr = lane & 15, quad = lane >> 4;                               \
  const int wm = (wave >> 1) * 64, wn = (wave & 1) * 64;                    \
  const int c0row = tid >> 2, colw = (tid & 3) * 8;

#define TILE_KLOOP(Abase, Bbase)                                            \
  const short* Ag0 = (Abase) + (long)(mblk + c0row) * DIM + colw;           \
  const short* Ag1 = (Abase) + (long)(mblk + 64 + c0row) * DIM + colw;      \
  const short* Bg0 = (Bbase) + (long)(nblk + c0row) * DIM + colw;           \
  const short* Bg1 = (Bbase) + (long)(nblk + 64 + c0row) * DIM + colw;      \
  short* Al0 = As + tid * 8;                                                \
  short* Al1 = As + 2048 + tid * 8;                                         \
  short* Bl0 = Bs + tid * 8;                                                \
  short* Bl1 = Bs + 2048 + tid * 8;                                         \
  f32x4 acc[4][4] = {};                                                     \
  for (int k0 = 0; k0 < DIM; k0 += 32) {                                    \
    load_lds16(Ag0 + k0, Al0);                                              \
    load_lds16(Ag1 + k0, Al1);                                              \
    load_lds16(Bg0 + k0, Bl0);                                              \
    load_lds16(Bg1 + k0, Bl1);                                              \
    asm volatile("s_waitcnt vmcnt(0)" ::: "memory");                        \
    __syncthreads();                                                        \
    bf16x8 af[4], bfr[4];                                                   \
    _Pragma("unroll") for (int it = 0; it < 4; ++it)                        \
        af[it] = *(const bf16x8*)(As + (wm + it * 16 + lr) * 32 + quad * 8);\
    _Pragma("unroll") for (int jt = 0; jt < 4; ++jt)                        \
        bfr[jt] = *(const bf16x8*)(Bs + (wn + jt * 16 + lr) * 32 + quad * 8);\
    _Pragma("unroll") for (int it = 0; it < 4; ++it)                        \
        _Pragma("unroll") for (int jt = 0; jt < 4; ++jt)                    \
            acc[it][jt] = mfma16(af[it], bfr[jt], acc[it][jt]);             \
    __syncthreads();                                                        \
  }

// ---- fused: blocks 0..35 = Mt GEMM (Mt = (WqT)^T-style NT product);
// blocks 36..4131 = x-convert + beta (vectorized). ----
__global__ __launch_bounds__(256) void mt_convert(const bf16* __restrict__ WkT,
                                                  const bf16* __restrict__ WqT,
                                                  bf16* __restrict__ Mt,
                                                  const void* __restrict__ x_raw,
                                                  const int* __restrict__ mask,
                                                  const float* __restrict__ bvec,
                                                  bf16* __restrict__ xb,
                                                  float* __restrict__ betas,
                                                  const int* __restrict__ flag) {
  const int bx = blockIdx.x;
  if (bx < 36) {
    const int mblk = (bx / 6) * 128, nblk = (bx % 6) * 128;
    TILE_DECLS
    TILE_KLOOP((const short*)WkT, (const short*)WqT)
#pragma unroll
    for (int it = 0; it < 4; ++it)
#pragma unroll
      for (int jt = 0; jt < 4; ++jt)
#pragma unroll
        for (int r = 0; r < 4; ++r)
          Mt[(long)(mblk + wm + it * 16 + quad * 4 + r) * DIM +
             nblk + wn + jt * 16 + lr] = __float2bfloat16(acc[it][jt][r]);
  } else {
    const int wave = threadIdx.x >> 6, lane = threadIdx.x & 63;
    const int n = (bx - 36) * 4 + wave;  // [0, 16384)
    const int f = *flag;
    short* xo = (short*)xb + (long)n * DIM;
    float s = 0.f;
    if (f) {
      const float4* x4 = (const float4*)((const float*)x_raw + (long)n * DIM);
      const float4* bv4 = (const float4*)bvec;
#pragma unroll
      for (int it = 0; it < 3; ++it) {
        const int idx = it * 64 + lane;
        const float4 v = x4[idx];
        const float4 bb = bv4[idx];
        short4v sv = {f2b(v.x), f2b(v.y), f2b(v.z), f2b(v.w)};
        *(short4v*)(xo + idx * 4) = sv;
        s += v.x * bb.x + v.y * bb.y + v.z * bb.z + v.w * bb.w;
      }
    } else {
      const short4v* x4 = (const short4v*)((const short*)x_raw + (long)n * DIM);
      const float4* bv4 = (const float4*)bvec;
#pragma unroll
      for (int it = 0; it < 3; ++it) {
        const int idx = it * 64 + lane;
        const short4v v = x4[idx];
        const float4 bb = bv4[idx];
        *(short4v*)(xo + idx * 4) = v;
        s += b2f(v.x) * bb.x + b2f(v.y) * bb.y + b2f(v.z) * bb.z + b2f(v.w) * bb.w;
      }
    }
#pragma unroll
    for (int off = 1; off < 64; off <<= 1) s += __shfl_xor(s, off, 64);
    if (lane == 0) betas[n] = mask[n] ? s * INV_SCALE : -1e30f;
  }
}

// ================= 256x256 8-phase counted-vmcnt NT GEMM core ==============
// 512 thr (8 waves, 2Mx4N), per-wave 128x64 C, BK=64, K=768 (12 tiles).
// LDS 128 KiB: [buf0.A | buf0.B | buf1.A | buf1.B], each 16384 shorts,
// tile T lives in buf[T&1]. Half-tile = 128 rows x 64 shorts = 8192 shorts.
// T2 swizzle (rule 21: both-sides): LDS linear for global_load_lds; the
// 16B k-chunk is permuted at the GLOBAL source (chunk ^= row&7) and the
// same XOR is applied on ds_read -> every bank hit exactly 8x (min).
// Schedule per iter t (consumes tiles 2t buf0 / 2t+1 buf1, stages 8 halves):
//  ph1 rd A0+B0(buf0), stg buf1.A0<-A0(2t+1) | ph2 rd B1, stg buf1.A1
//  ph3 rd A1,          stg buf0.B0<-B0(2t+2) | ph4 stg buf0.B1, vmcnt(4)
//  ph5 rd buf1,        stg buf0.A0<-A0(2t+2) | ph6 rd B1, stg buf0.A1
//  ph7 rd A1,          stg buf1.B0<-B0(2t+3) | ph8 stg buf1.B1, vmcnt(4)
// vmcnt(4) leaves the 2 newest half-tiles in flight; never 0 in main loop.

#define BARX() asm volatile("s_barrier" ::: "memory")
#define LGKM0() asm volatile("s_waitcnt lgkmcnt(0)" ::: "memory")
#define VMC4() asm volatile("s_waitcnt vmcnt(4)" ::: "memory")
#define VMC0() asm volatile("s_waitcnt vmcnt(0)" ::: "memory")

__device__ __forceinline__ void core256(const short* A, const short* B,
                                        short* sh, f32x4 (&acc)[8][4],
                                        const int wm, const int wn,
                                        const int lr, const int quad,
                                        const int tid) {
  const int sw7 = lr & 7;
  const int cof0 = (quad ^ sw7) * 8;        // ds_read chunk XOR, ks=0
  const int cof1 = ((quad + 4) ^ sw7) * 8;  // ks=1
  const int rS = tid >> 3;                  // staging row 0..63 (per half)
  const int cS8 = ((tid & 7) ^ (rS & 7)) * 8;  // pre-swizzled source chunk
  const short* aP0 = A + (long)rS * DIM + cS8;
  const short* aP1 = aP0 + 128 * DIM;
  const short* bP0 = B + (long)rS * DIM + cS8;
  const short* bP1 = bP0 + 128 * DIM;
  short* l0 = sh + tid * 8;
  short* l1 = sh + 4096 + tid * 8;
  bf16x8 af0[4][2], af1[4][2], bf0[2][2], bf1[2][2];

#define STG(BASE, GP, K0)                              \
  do {                                                 \
    load_lds16((GP) + (K0), l0 + (BASE));              \
    load_lds16((GP) + 64 * DIM + (K0), l1 + (BASE));   \
  } while (0)
#define READ_AF0(AB)                                                \
  _Pragma("unroll") for (int f_ = 0; f_ < 4; ++f_) {                \
    const int ro_ = (AB) + (wm + f_ * 16 + lr) * 64;                \
    af0[f_][0] = *(const bf16x8*)(sh + ro_ + cof0);                 \
    af0[f_][1] = *(const bf16x8*)(sh + ro_ + cof1);                 \
  }
#define READ_AF1(AB)                                                \
  _Pragma("unroll") for (int f_ = 0; f_ < 4; ++f_) {                \
    const int ro_ = (AB) + (wm + 64 + f_ * 16 + lr) * 64;           \
    af1[f_][0] = *(const bf16x8*)(sh + ro_ + cof0);                 \
    af1[f_][1] = *(const bf16x8*)(sh + ro_ + cof1);                 \
  }
#define READ_BF0(BB)                                                \
  _Pragma("unroll") for (int f_ = 0; f_ < 2; ++f_) {                \
    const int ro_ = (BB) + (wn + f_ * 16 + lr) * 64;                \
    bf0[f_][0] = *(const bf16x8*)(sh + ro_ + cof0);                 \
    bf0[f_][1] = *(const bf16x8*)(sh + ro_ + cof1);                 \
  }
#define READ_BF1(BB)                                                \
  _Pragma("unroll") for (int f_ = 0; f_ < 2; ++f_) {                \
    const int ro_ = (BB) + (wn + 32 + f_ * 16 + lr) * 64;           \
    bf1[f_][0] = *(const bf16x8*)(sh + ro_ + cof0);                 \
    bf1[f_][1] = *(const bf16x8*)(sh + ro_ + cof1);                 \
  }
#define MMA8(AF, BF, FIO, FJO)                                            \
  _Pragma("unroll") for (int i_ = 0; i_ < 4; ++i_)                        \
  _Pragma("unroll") for (int j_ = 0; j_ < 2; ++j_) {                      \
    acc[i_ + (FIO)][j_ + (FJO)] =                                         \
        mfma16(AF[i_][0], BF[j_][0], acc[i_ + (FIO)][j_ + (FJO)]);        \
    acc[i_ + (FIO)][j_ + (FJO)] =                                         \
        mfma16(AF[i_][1], BF[j_][1], acc[i_ + (FIO)][j_ + (FJO)]);        \
  }

  // prologue: B0(0) B1(0) A0(0) A1(0) B0(1) B1(1); drain tile 0.
  STG(16384, bP0, 0); STG(24576, bP1, 0);
  STG(0, aP0, 0);     STG(8192, aP1, 0);
  STG(49152, bP0, 64); STG(57344, bP1, 64);
  VMC4();
  BARX();

#pragma unroll 1
  for (int t = 0; t < 5; ++t) {
    const int kA1 = (2 * t + 1) * 64;
    const int kB2 = kA1 + 64;
    const int kB3 = kB2 + 64;
    // ph1
    READ_AF0(0) READ_BF0(16384)
    STG(32768, aP0, kA1);
    BARX(); LGKM0(); __builtin_amdgcn_s_setprio(1);
    MMA8(af0, bf0, 0, 0) __builtin_amdgcn_s_setprio(0); BARX();
    // ph2
    READ_BF1(16384)
    STG(40960, aP1, kA1);
    BARX(); LGKM0(); __builtin_amdgcn_s_setprio(1);
    MMA8(af0, bf1, 0, 2) __builtin_amdgcn_s_setprio(0); BARX();
    // ph3
    READ_AF1(0)
    STG(16384, bP0, kB2);
    BARX(); LGKM0(); __builtin_amdgcn_s_setprio(1);
    MMA8(af1, bf0, 4, 0) __builtin_amdgcn_s_setprio(0); BARX();
    // ph4
    STG(24576, bP1, kB2);
    VMC4();
    BARX(); __builtin_amdgcn_s_setprio(1);
    MMA8(af1, bf1, 4, 2) __builtin_amdgcn_s_setprio(0); BARX();
    // ph5
    READ_AF0(32768) READ_BF0(49152)
    STG(0, aP0, kB2);
    BARX(); LGKM0(); __builtin_amdgcn_s_setprio(1);
    MMA8(af0, bf0, 0, 0) __builtin_amdgcn_s_setprio(0); BARX();
    // ph6
    READ_BF1(49152)
    STG(8192, aP1, kB2);
    BARX(); LGKM0(); __builtin_amdgcn_s_setprio(1);
    MMA8(af0, bf1, 0, 2) __builtin_amdgcn_s_setprio(0); BARX();
    // ph7
    READ_AF1(32768)
    STG(49152, bP0, kB3);
    BARX(); LGKM0(); __builtin_amdgcn_s_setprio(1);
    MMA8(af1, bf0, 4, 0) __builtin_amdgcn_s_setprio(0); BARX();
    // ph8
    STG(57344, bP1, kB3);
    VMC4();
    BARX(); __builtin_amdgcn_s_setprio(1);
    MMA8(af1, bf1, 4, 2) __builtin_amdgcn_s_setprio(0); BARX();
  }

  // tail: tiles 10 (buf0) and 11 (buf1); only A(11) remains to stage (k=704).
  // ph1
  READ_AF0(0) READ_BF0(16384)
  STG(32768, aP0, 704);
  BARX(); LGKM0(); __builtin_amdgcn_s_setprio(1);
  MMA8(af0, bf0, 0, 0) __builtin_amdgcn_s_setprio(0); BARX();
  // ph2
  READ_BF1(16384)
  STG(40960, aP1, 704);
  BARX(); LGKM0(); __builtin_amdgcn_s_setprio(1);
  MMA8(af0, bf1, 0, 2) __builtin_amdgcn_s_setprio(0); BARX();
  // ph3
  READ_AF1(0)
  BARX(); LGKM0(); __builtin_amdgcn_s_setprio(1);
  MMA8(af1, bf0, 4, 0) __builtin_amdgcn_s_setprio(0); BARX();
  // ph4
  VMC0();
  BARX(); __builtin_amdgcn_s_setprio(1);
  MMA8(af1, bf1, 4, 2) __builtin_amdgcn_s_setprio(0); BARX();
  // ph5
  READ_AF0(32768) READ_BF0(49152)
  BARX(); LGKM0(); __builtin_amdgcn_s_setprio(1);
  MMA8(af0, bf0, 0, 0) __builtin_amdgcn_s_setprio(0); BARX();
  // ph6
  READ_BF1(49152)
  BARX(); LGKM0(); __builtin_amdgcn_s_setprio(1);
  MMA8(af0, bf1, 0, 2) __builtin_amdgcn_s_setprio(0); BARX();
  // ph7
  READ_AF1(32768)
  BARX(); LGKM0(); __builtin_amdgcn_s_setprio(1);
  MMA8(af1, bf0, 4, 0) __builtin_amdgcn_s_setprio(0); BARX();
  // ph8
  __builtin_amdgcn_s_setprio(1);
  MMA8(af1, bf1, 4, 2) __builtin_amdgcn_s_setprio(0);

#undef STG
#undef READ_AF0
#undef READ_AF1
#undef READ_BF0
#undef READ_BF1
#undef MMA8
}

// ---- z = A @ B^T (NT, ld=768): 256x256 tiles, grid (M/256, 3) ----
__global__ __launch_bounds__(512, 2) void gemm_nt_256(const bf16* __restrict__ A,
                                                      const bf16* __restrict__ B,
                                                      bf16* __restrict__ D) {
  __shared__ __align__(16) short sh[65536];
  const int tid = threadIdx.x;
  const int wave = tid >> 6, lane = tid & 63;
  const int lr = lane & 15, quad = lane >> 4;
  const int wm = (wave >> 2) * 128, wn = (wave & 3) * 64;
  const int mblk = blockIdx.x * 256, nblk = blockIdx.y * 256;
  f32x4 acc[8][4] = {};
  core256((const short*)A + (long)mblk * DIM, (const short*)B + (long)nblk * DIM,
          sh, acc, wm, wn, lr, quad, tid);
#pragma unroll
  for (int fi = 0; fi < 8; ++fi)
#pragma unroll
    for (int fj = 0; fj < 4; ++fj)
#pragma unroll
      for (int r = 0; r < 4; ++r)
        D[(long)(mblk + wm + fi * 16 + quad * 4 + r) * DIM +
          nblk + wn + fj * 16 + lr] = __float2bfloat16(acc[fi][fj][r]);
}

// ---- fused score: ONE GEMM; epilogue A accumulates l rowsums (atomics),
// cross-block sync per (b, mtile) group of 8 via device-scope counter
// (all blocks co-resident: grid <= 256, 1 block/CU), then epilogue B
// weights with rq (atomic coherent readback of l) and column-reduces to c.
// Grid nb*64 (nb <= 4), XCD-remapped: group's 8 blocks are bid-consecutive
// within one XCD chunk -> they arrive at the sync nearly together. ----
__global__ __launch_bounds__(512, 2) void gemm_score_fused(const bf16* __restrict__ z,
                                                           const bf16* __restrict__ x,
                                                           const float* __restrict__ betas,
                                                           float* __restrict__ l_out,
                                                           float* __restrict__ c,
                                                           int* __restrict__ cnt,
                                                           int b0) {
  __shared__ __align__(16) short sh[65536];
  const int nwg = (int)gridDim.x;
  const int cpx = nwg >> 3;  // nwg is a multiple of 8 (nb*64)
  const int bid = (blockIdx.x & 7) * cpx + (blockIdx.x >> 3);
  const int lb = bid >> 6, rb = bid & 63;
  const int mblk = (rb >> 3) * 256, nblk = (rb & 7) * 256;
  const int b = b0 + lb;
  const int tid = threadIdx.x;
  const int wave = tid >> 6, lane = tid & 63;
  const int lr = lane & 15, quad = lane >> 4;
  const int wm = (wave >> 2) * 128, wn = (wave & 3) * 64;
  f32x4 acc[8][4] = {};
  core256((const short*)z + (long)lb * S * DIM + (long)mblk * DIM,
          (const short*)x + (long)b * S * DIM + (long)nblk * DIM,
          sh, acc, wm, wn, lr, quad, tid);
  float bet[4];
#pragma unroll
  for (int fj = 0; fj < 4; ++fj)
    bet[fj] = betas[b * S + nblk + wn + fj * 16 + lr];
  // ---- epilogue A: rowsum partials -> l (device-scope atomics) ----
  float* lrow = l_out + b * S;
#pragma unroll
  for (int fi = 0; fi < 8; ++fi) {
#pragma unroll
    for (int r = 0; r < 4; ++r) {
      const int q = mblk + wm + fi * 16 + quad * 4 + r;
      float s = 0.f;
#pragma unroll
      for (int fj = 0; fj < 4; ++fj)
        s += __expf(fminf(acc[fi][fj][r] * INV_SCALE + bet[fj], 60.f));
      s += __shfl_xor(s, 1, 64);
      s += __shfl_xor(s, 2, 64);
      s += __shfl_xor(s, 4, 64);
      s += __shfl_xor(s, 8, 64);
      if (lr == 0) atomicAdd(&lrow[q], s);
    }
  }
  // ---- cross-block sync: 8 n-blocks per (b, mtile) group ----
  asm volatile("s_waitcnt vmcnt(0)" ::: "memory");  // drain this thread's atomics
  __threadfence();                                  // device-wide visibility
  __syncthreads();                                  // whole block's atomics done
  int* cp = cnt + b * 8 + (rb >> 3);
  if (tid == 0) {
    const int prev = atomicAdd(cp, 1);
    if (prev + 1 < 8) {
      while (atomicAdd(cp, 0) < 8) __builtin_amdgcn_s_sleep(8);
    }
  }
  __syncthreads();
  // ---- epilogue B: stage rq (coherent atomic reads), weight, reduce to c ----
  float* lds_rq = (float*)sh;          // [256]
  float* cred = (float*)sh + 256;      // [4 waves][4 fj][16 lr]
  if (tid < 256) {
    const float lv = atomicAdd(&l_out[b * S + mblk + tid], 0.0f);
    lds_rq[tid] = lv > 0.f ? 1.0f / lv : 0.f;
  }
  __syncthreads();
  float csum[4] = {};
#pragma unroll
  for (int fi = 0; fi < 8; ++fi) {
#pragma unroll
    for (int r = 0; r < 4; ++r) {
      const float rqv = lds_rq[wm + fi * 16 + quad * 4 + r];
#pragma unroll
      for (int fj = 0; fj < 4; ++fj)
        csum[fj] += __expf(fminf(acc[fi][fj][r] * INV_SCALE + bet[fj], 60.f)) * rqv;
    }
  }
#pragma unroll
  for (int fj = 0; fj < 4; ++fj) {
    csum[fj] += __shfl_xor(csum[fj], 16, 64);
    csum[fj] += __shfl_xor(csum[fj], 32, 64);
  }
  if (wave >= 4 && quad == 0) {
#pragma unroll
    for (int fj = 0; fj < 4; ++fj)
      cred[((wave & 3) * 4 + fj) * 16 + lr] = csum[fj];
  }
  __syncthreads();
  if (wave < 4 && quad == 0) {
#pragma unroll
    for (int fj = 0; fj < 4; ++fj)
      atomicAdd(&c[b * S + nblk + wn + fj * 16 + lr],
                (csum[fj] + cred[(wave * 4 + fj) * 16 + lr]) * (1.0f / 2048.0f));
  }
}

// ---- y[b,i] = sum_k c[b,k]*x[b,k,i]; grid (3, 16, 8), k-chunk 128 ----
__global__ __launch_bounds__(256) void y_kernel(const bf16* __restrict__ x,
                                                const float* __restrict__ c,
                                                float* __restrict__ y) {
  const int b = blockIdx.z;
  const int i = blockIdx.x * 256 + threadIdx.x;
  const int kstart = blockIdx.y * 128;
  const bf16* xb = x + (long)(b * S + kstart) * DIM + i;
  const float* cb = c + b * S + kstart;
  float acc = 0.f;
  for (int k = 0; k < 128; ++k)
    acc += cb[k] * __bfloat162float(xb[(long)k * DIM]);
  atomicAdd(&y[b * DIM + i], acc);
}

// ---- out[b,o] = y_b . Wv[o,:] + bv[o] (raw Wv/bv, dtype per flag) ----
// grid 1536 x 256: one wave per (b,o) row, vectorized.
__global__ __launch_bounds__(256) void out_kernel(const float* __restrict__ y,
                                                  const void* __restrict__ Wv_raw,
                                                  const void* __restrict__ bv_raw,
                                                  void* __restrict__ out,
                                                  const int* __restrict__ flag) {
  const int wave = threadIdx.x >> 6, lane = threadIdx.x & 63;
  const int w = blockIdx.x * 4 + wave;  // [0, 6144)
  const int b = w / DIM, o = w % DIM;
  const int f = *flag;
  const float4* y4 = (const float4*)(y + (long)b * DIM);
  float s = 0.f;
  if (f) {
    const float4* wr = (const float4*)((const float*)Wv_raw + (long)o * DIM);
#pragma unroll
    for (int it = 0; it < 3; ++it) {
      const int idx = it * 64 + lane;
      const float4 a = y4[idx], wv = wr[idx];
      s += a.x * wv.x + a.y * wv.y + a.z * wv.z + a.w * wv.w;
    }
  } else {
    const short4v* wr = (const short4v*)((const short*)Wv_raw + (long)o * DIM);
#pragma unroll
    for (int it = 0; it < 3; ++it) {
      const int idx = it * 64 + lane;
      const float4 a = y4[idx];
      const short4v wv = wr[idx];
      s += a.x * b2f(wv.x) + a.y * b2f(wv.y) + a.z * b2f(wv.z) + a.w * b2f(wv.w);
    }
  }
#pragma unroll
  for (int off = 1; off < 64; off <<= 1) s += __shfl_xor(s, off, 64);
  if (lane == 0) {
    const float bias = f ? ((const float*)bv_raw)[o] : b2f(((const short*)bv_raw)[o]);
    const float v = s + bias;
    if (f) ((float*)out)[b * DIM + o] = v;
    else ((bf16*)out)[b * DIM + o] = __float2bfloat16(v);
  }
}

extern "C" void kernel_launch(void* const* d_in, const int* in_sizes, int n_in,
                              void* d_out, int out_size, void* d_ws, size_t ws_size,
                              hipStream_t stream) {
  const void* x_raw = d_in[0];
  const int* mask = (const int*)d_in[1];
  const void* Wq_raw = d_in[2];
  const void* bq_raw = d_in[3];
  const void* Wk_raw = d_in[4];
  // d_in[5] = bk: provably cancels out of the computation.
  const void* Wv_raw = d_in[6];
  const void* bv_raw = d_in[7];

  char* ws = (char*)d_ws;
  bf16* xb = (bf16*)(ws);                   //          0 .. 25,165,824
  bf16* WqT = (bf16*)(ws + 25165824);       // 1,179,648 B
  bf16* WkT = (bf16*)(ws + 26345472);       // 1,179,648 B
  bf16* Mt = (bf16*)(ws + 27525120);        // 1,179,648 B  Mt[j,i]=M[i,j]
  float* betas = (float*)(ws + 28704768);   //    65,536 B
  // ---- zeroed region starts here ----
  float* bvec = (float*)(ws + 28770304);    //     3,072 B
  float* l = (float*)(ws + 28773376);       //    65,536 B
  float* c = (float*)(ws + 28838912);       //    65,536 B
  float* y = (float*)(ws + 28904448);       //    24,576 B
  int* flag = (int*)(ws + 28929024);        //        64 B
  int* cnt = (int*)(ws + 28929088);         //       256 B (64 group counters)
  bf16* z = (bf16*)(ws + 28929344);         // nb * 3,145,728 B

  const size_t fixed = 28929344;
  const size_t zb = 3145728;  // per-batch z bytes
  // nb capped at 4: the fused score kernel's grid (nb*64 <= 256 blocks,
  // 1 block/CU) must be fully co-resident for the cross-block sync.
  int nb = 1;
  if (ws_size >= fixed + 4 * zb) nb = 4;
  else if (ws_size >= fixed + 2 * zb) nb = 2;
  const int rounds = BATCH / nb;

  // zero bvec, l, c, y, flag, cnt (contiguous)
  (void)hipMemsetAsync(bvec, 0, 3072 + 65536 + 65536 + 24576 + 64 + 256, stream);

  detect_dtype<<<1, 256, 0, stream>>>((const unsigned short*)x_raw, flag);
  prep_kernel<<<294, 256, 0, stream>>>(Wq_raw, Wk_raw, bq_raw, WqT, WkT, bvec, flag);
  mt_convert<<<4132, 256, 0, stream>>>(WkT, WqT, Mt, x_raw, mask, bvec, xb,
                                       betas, flag);

  for (int r = 0; r < rounds; ++r) {
    const int b0 = r * nb;
    // z[lb*S+q, :] = x[b0+lb, q, :] @ M
    gemm_nt_256<<<dim3(nb * 8, 3), 512, 0, stream>>>(
        xb + (long)b0 * S * DIM, Mt, z);
    gemm_score_fused<<<nb * 64, 512, 0, stream>>>(z, xb, betas, l, c, cnt, b0);
  }

  y_kernel<<<dim3(3, 16, 8), 256, 0, stream>>>(xb, c, y);
  out_kernel<<<1536, 256, 0, stream>>>(y, Wv_raw, bv_raw, d_out, flag);
}

// Round 7
// 265.421 us; speedup vs baseline: 1.1860x; 1.1860x over previous
//
#include <hip/hip_runtime.h>
#include <hip/hip_bf16.h>

// AttentionPoolingAdvance: B=8,S=2048,D=768 (fp32 in/out, detected on device).
// out[b] = mean_q softmax((Q K^T)/sqrt(D), key-mask) V
// Algebra: out = (c^T x) Wv^T + bv with c_k=(1/S) sum_q w[q,k];
// score[q,k] == (z_q.x_k)/sqrt(D) + beta_k modulo softmax-invariant terms,
// z = x @ (Wq^T Wk), beta_k = x_k.(Wk^T bq)/sqrt(D); bk cancels.
// Round 14: revert round-13 fusion (group-straggler serialization at
// 1 block/CU made it 2x slower per work). Back to two-pass flash-style
// (270 us) + consolidation: detect_dtype launch removed — prep self-detects
// dtype inline and publishes the flag for downstream kernels.

#define S 2048
#define DIM 768
#define BATCH 8

typedef __hip_bfloat16 bf16;
typedef __attribute__((ext_vector_type(8))) short bf16x8;
typedef __attribute__((ext_vector_type(4))) short short4v;
typedef __attribute__((ext_vector_type(4))) float f32x4;

__device__ __forceinline__ f32x4 mfma16(bf16x8 a, bf16x8 b, f32x4 c) {
  return __builtin_amdgcn_mfma_f32_16x16x32_bf16(a, b, c, 0, 0, 0);
}

__device__ __forceinline__ void load_lds16(const short* g, short* l) {
  __builtin_amdgcn_global_load_lds(
      (const __attribute__((address_space(1))) unsigned int*)g,
      (__attribute__((address_space(3))) unsigned int*)l, 16, 0, 0);
}

__device__ __forceinline__ float b2f(short u) {
  union { float f; unsigned u; } v;
  v.u = ((unsigned)(unsigned short)u) << 16;
  return v.f;
}

__device__ __forceinline__ short f2b(float f) {
  bf16 h = __float2bfloat16(f);
  return *(short*)&h;
}

#define INV_SCALE 0.03608439182435161f  // 1/sqrt(768)

// ---- prep: blocks 0..287 transpose Wq/Wk -> bf16 T; 288..293 bvec partials.
// Each block inline-detects dtype from x (bf16 N(0,1) halfwords have exp
// field in ~[0x60,0x9F); fp32 mantissa halfwords are ~uniform). Block 0
// publishes the flag for downstream kernels (1 => fp32 inputs).
__global__ __launch_bounds__(256) void prep_kernel(const void* __restrict__ x_raw,
                                                   const void* __restrict__ Wq_raw,
                                                   const void* __restrict__ Wk_raw,
                                                   const void* __restrict__ bq_raw,
                                                   bf16* __restrict__ T0,
                                                   bf16* __restrict__ T1,
                                                   float* __restrict__ bvec,
                                                   int* __restrict__ flag) {
  __shared__ int sf[4];
  const int bx = blockIdx.x;
  // inline dtype detect (all blocks; 4 KB, L2-broadcast)
  {
    const unsigned short* xh = (const unsigned short*)x_raw;
    int bad = 0;
    for (int i = threadIdx.x; i < 2048; i += 256) {
      int e = (xh[i] >> 7) & 0xFF;
      if (e < 0x60 || e >= 0x9F) bad = 1;
    }
    bad = __any(bad);
    if ((threadIdx.x & 63) == 0) sf[threadIdx.x >> 6] = bad;
  }
  __syncthreads();
  const int f = sf[0] | sf[1] | sf[2] | sf[3];
  if (bx == 0 && threadIdx.x == 0 && f) atomicOr(flag, 1);

  if (bx < 288) {
    __shared__ unsigned short tile[64][66];
    const int p = bx / 144, r = bx % 144;
    const void* src = p ? Wk_raw : Wq_raw;
    unsigned short* dst = (unsigned short*)(p ? T1 : T0);
    const int obase = (r / 12) * 64, ibase = (r % 12) * 64;
    const int col = threadIdx.x & 63, rq = threadIdx.x >> 6;
#pragma unroll
    for (int rr = 0; rr < 64; rr += 4) {
      const long idx = (long)(obase + rr + rq) * DIM + ibase + col;
      const float v = f ? ((const float*)src)[idx] : b2f(((const short*)src)[idx]);
      tile[rr + rq][col] = (unsigned short)f2b(v);
    }
    __syncthreads();
#pragma unroll
    for (int rr = 0; rr < 64; rr += 4)
      dst[(long)(ibase + rr + rq) * DIM + obase + col] = tile[col][rr + rq];
  } else {
    const int o0 = (bx - 288) * 128;
    const int t = threadIdx.x;
    float s0 = 0.f, s1 = 0.f, s2 = 0.f;
    if (f) {
      const float* W = (const float*)Wk_raw;
      const float* bq = (const float*)bq_raw;
      for (int o = o0; o < o0 + 128; ++o) {
        const float bo = bq[o];
        const float* row = W + (long)o * DIM;
        s0 += row[t] * bo;
        s1 += row[t + 256] * bo;
        s2 += row[t + 512] * bo;
      }
    } else {
      const short* W = (const short*)Wk_raw;
      const short* bq = (const short*)bq_raw;
      for (int o = o0; o < o0 + 128; ++o) {
        const float bo = b2f(bq[o]);
        const short* row = W + (long)o * DIM;
        s0 += b2f(row[t]) * bo;
        s1 += b2f(row[t + 256]) * bo;
        s2 += b2f(row[t + 512]) * bo;
      }
    }
    atomicAdd(&bvec[t], s0);
    atomicAdd(&bvec[t + 256], s1);
    atomicAdd(&bvec[t + 512], s2);
  }
}

// ================= m97-style tiled NT GEMM core (kept for mt_convert) ======
// 128x128 C-tile per 256-thread block (4 waves, 2x2), BK=32, K=768,
// A,B row-major ld=768. Staging via global_load_lds width 16.
#define TILE_DECLS                                                          \
  __shared__ short As[4096], Bs[4096];                                      \
  const int tid = threadIdx.x;                                              \
  const int wave = tid >> 6, lane = tid & 63;                               \
  const int lr = lane & 15, quad = lane >> 4;                               \
  const int wm = (wave >> 1) * 64, wn = (wave & 1) * 64;                    \
  const int c0row = tid >> 2, colw = (tid & 3) * 8;

#define TILE_KLOOP(Abase, Bbase)                                            \
  const short* Ag0 = (Abase) + (long)(mblk + c0row) * DIM + colw;           \
  const short* Ag1 = (Abase) + (long)(mblk + 64 + c0row) * DIM + colw;      \
  const short* Bg0 = (Bbase) + (long)(nblk + c0row) * DIM + colw;           \
  const short* Bg1 = (Bbase) + (long)(nblk + 64 + c0row) * DIM + colw;      \
  short* Al0 = As + tid * 8;                                                \
  short* Al1 = As + 2048 + tid * 8;                                         \
  short* Bl0 = Bs + tid * 8;                                                \
  short* Bl1 = Bs + 2048 + tid * 8;                                         \
  f32x4 acc[4][4] = {};                                                     \
  for (int k0 = 0; k0 < DIM; k0 += 32) {                                    \
    load_lds16(Ag0 + k0, Al0);                                              \
    load_lds16(Ag1 + k0, Al1);                                              \
    load_lds16(Bg0 + k0, Bl0);                                              \
    load_lds16(Bg1 + k0, Bl1);                                              \
    asm volatile("s_waitcnt vmcnt(0)" ::: "memory");                        \
    __syncthreads();                                                        \
    bf16x8 af[4], bfr[4];                                                   \
    _Pragma("unroll") for (int it = 0; it < 4; ++it)                        \
        af[it] = *(const bf16x8*)(As + (wm + it * 16 + lr) * 32 + quad * 8);\
    _Pragma("unroll") for (int jt = 0; jt < 4; ++jt)                        \
        bfr[jt] = *(const bf16x8*)(Bs + (wn + jt * 16 + lr) * 32 + quad * 8);\
    _Pragma("unroll") for (int it = 0; it < 4; ++it)                        \
        _Pragma("unroll") for (int jt = 0; jt < 4; ++jt)                    \
            acc[it][jt] = mfma16(af[it], bfr[jt], acc[it][jt]);             \
    __syncthreads();                                                        \
  }

// ---- fused: blocks 0..35 = Mt GEMM (Mt = (WqT)^T-style NT product);
// blocks 36..4131 = x-convert + beta (vectorized). ----
__global__ __launch_bounds__(256) void mt_convert(const bf16* __restrict__ WkT,
                                                  const bf16* __restrict__ WqT,
                                                  bf16* __restrict__ Mt,
                                                  const void* __restrict__ x_raw,
                                                  const int* __restrict__ mask,
                                                  const float* __restrict__ bvec,
                                                  bf16* __restrict__ xb,
                                                  float* __restrict__ betas,
                                                  const int* __restrict__ flag) {
  const int bx = blockIdx.x;
  if (bx < 36) {
    const int mblk = (bx / 6) * 128, nblk = (bx % 6) * 128;
    TILE_DECLS
    TILE_KLOOP((const short*)WkT, (const short*)WqT)
#pragma unroll
    for (int it = 0; it < 4; ++it)
#pragma unroll
      for (int jt = 0; jt < 4; ++jt)
#pragma unroll
        for (int r = 0; r < 4; ++r)
          Mt[(long)(mblk + wm + it * 16 + quad * 4 + r) * DIM +
             nblk + wn + jt * 16 + lr] = __float2bfloat16(acc[it][jt][r]);
  } else {
    const int wave = threadIdx.x >> 6, lane = threadIdx.x & 63;
    const int n = (bx - 36) * 4 + wave;  // [0, 16384)
    const int f = *flag;
    short* xo = (short*)xb + (long)n * DIM;
    float s = 0.f;
    if (f) {
      const float4* x4 = (const float4*)((const float*)x_raw + (long)n * DIM);
      const float4* bv4 = (const float4*)bvec;
#pragma unroll
      for (int it = 0; it < 3; ++it) {
        const int idx = it * 64 + lane;
        const float4 v = x4[idx];
        const float4 bb = bv4[idx];
        short4v sv = {f2b(v.x), f2b(v.y), f2b(v.z), f2b(v.w)};
        *(short4v*)(xo + idx * 4) = sv;
        s += v.x * bb.x + v.y * bb.y + v.z * bb.z + v.w * bb.w;
      }
    } else {
      const short4v* x4 = (const short4v*)((const short*)x_raw + (long)n * DIM);
      const float4* bv4 = (const float4*)bvec;
#pragma unroll
      for (int it = 0; it < 3; ++it) {
        const int idx = it * 64 + lane;
        const short4v v = x4[idx];
        const float4 bb = bv4[idx];
        *(short4v*)(xo + idx * 4) = v;
        s += b2f(v.x) * bb.x + b2f(v.y) * bb.y + b2f(v.z) * bb.z + b2f(v.w) * bb.w;
      }
    }
#pragma unroll
    for (int off = 1; off < 64; off <<= 1) s += __shfl_xor(s, off, 64);
    if (lane == 0) betas[n] = mask[n] ? s * INV_SCALE : -1e30f;
  }
}

// ================= 256x256 8-phase counted-vmcnt NT GEMM core ==============
// 512 thr (8 waves, 2Mx4N), per-wave 128x64 C, BK=64, K=768 (12 tiles).
// LDS 128 KiB: [buf0.A | buf0.B | buf1.A | buf1.B], each 16384 shorts,
// tile T lives in buf[T&1]. Half-tile = 128 rows x 64 shorts = 8192 shorts.
// T2 swizzle (rule 21: both-sides): LDS linear for global_load_lds; the
// 16B k-chunk is permuted at the GLOBAL source (chunk ^= row&7) and the
// same XOR is applied on ds_read -> every bank hit exactly 8x (min).
// vmcnt(4) twice per iter, never 0 in the main loop.

#define BARX() asm volatile("s_barrier" ::: "memory")
#define LGKM0() asm volatile("s_waitcnt lgkmcnt(0)" ::: "memory")
#define VMC4() asm volatile("s_waitcnt vmcnt(4)" ::: "memory")
#define VMC0() asm volatile("s_waitcnt vmcnt(0)" ::: "memory")

__device__ __forceinline__ void core256(const short* A, const short* B,
                                        short* sh, f32x4 (&acc)[8][4],
                                        const int wm, const int wn,
                                        const int lr, const int quad,
                                        const int tid) {
  const int sw7 = lr & 7;
  const int cof0 = (quad ^ sw7) * 8;        // ds_read chunk XOR, ks=0
  const int cof1 = ((quad + 4) ^ sw7) * 8;  // ks=1
  const int rS = tid >> 3;                  // staging row 0..63 (per half)
  const int cS8 = ((tid & 7) ^ (rS & 7)) * 8;  // pre-swizzled source chunk
  const short* aP0 = A + (long)rS * DIM + cS8;
  const short* aP1 = aP0 + 128 * DIM;
  const short* bP0 = B + (long)rS * DIM + cS8;
  const short* bP1 = bP0 + 128 * DIM;
  short* l0 = sh + tid * 8;
  short* l1 = sh + 4096 + tid * 8;
  bf16x8 af0[4][2], af1[4][2], bf0[2][2], bf1[2][2];

#define STG(BASE, GP, K0)                              \
  do {                                                 \
    load_lds16((GP) + (K0), l0 + (BASE));              \
    load_lds16((GP) + 64 * DIM + (K0), l1 + (BASE));   \
  } while (0)
#define READ_AF0(AB)                                                \
  _Pragma("unroll") for (int f_ = 0; f_ < 4; ++f_) {                \
    const int ro_ = (AB) + (wm + f_ * 16 + lr) * 64;                \
    af0[f_][0] = *(const bf16x8*)(sh + ro_ + cof0);                 \
    af0[f_][1] = *(const bf16x8*)(sh + ro_ + cof1);                 \
  }
#define READ_AF1(AB)                                                \
  _Pragma("unroll") for (int f_ = 0; f_ < 4; ++f_) {                \
    const int ro_ = (AB) + (wm + 64 + f_ * 16 + lr) * 64;           \
    af1[f_][0] = *(const bf16x8*)(sh + ro_ + cof0);                 \
    af1[f_][1] = *(const bf16x8*)(sh + ro_ + cof1);                 \
  }
#define READ_BF0(BB)                                                \
  _Pragma("unroll") for (int f_ = 0; f_ < 2; ++f_) {                \
    const int ro_ = (BB) + (wn + f_ * 16 + lr) * 64;                \
    bf0[f_][0] = *(const bf16x8*)(sh + ro_ + cof0);                 \
    bf0[f_][1] = *(const bf16x8*)(sh + ro_ + cof1);                 \
  }
#define READ_BF1(BB)                                                \
  _Pragma("unroll") for (int f_ = 0; f_ < 2; ++f_) {                \
    const int ro_ = (BB) + (wn + 32 + f_ * 16 + lr) * 64;           \
    bf1[f_][0] = *(const bf16x8*)(sh + ro_ + cof0);                 \
    bf1[f_][1] = *(const bf16x8*)(sh + ro_ + cof1);                 \
  }
#define MMA8(AF, BF, FIO, FJO)                                            \
  _Pragma("unroll") for (int i_ = 0; i_ < 4; ++i_)                        \
  _Pragma("unroll") for (int j_ = 0; j_ < 2; ++j_) {                      \
    acc[i_ + (FIO)][j_ + (FJO)] =                                         \
        mfma16(AF[i_][0], BF[j_][0], acc[i_ + (FIO)][j_ + (FJO)]);        \
    acc[i_ + (FIO)][j_ + (FJO)] =                                         \
        mfma16(AF[i_][1], BF[j_][1], acc[i_ + (FIO)][j_ + (FJO)]);        \
  }

  // prologue: B0(0) B1(0) A0(0) A1(0) B0(1) B1(1); drain tile 0.
  STG(16384, bP0, 0); STG(24576, bP1, 0);
  STG(0, aP0, 0);     STG(8192, aP1, 0);
  STG(49152, bP0, 64); STG(57344, bP1, 64);
  VMC4();
  BARX();

#pragma unroll 1
  for (int t = 0; t < 5; ++t) {
    const int kA1 = (2 * t + 1) * 64;
    const int kB2 = kA1 + 64;
    const int kB3 = kB2 + 64;
    // ph1
    READ_AF0(0) READ_BF0(16384)
    STG(32768, aP0, kA1);
    BARX(); LGKM0(); __builtin_amdgcn_s_setprio(1);
    MMA8(af0, bf0, 0, 0) __builtin_amdgcn_s_setprio(0); BARX();
    // ph2
    READ_BF1(16384)
    STG(40960, aP1, kA1);
    BARX(); LGKM0(); __builtin_amdgcn_s_setprio(1);
    MMA8(af0, bf1, 0, 2) __builtin_amdgcn_s_setprio(0); BARX();
    // ph3
    READ_AF1(0)
    STG(16384, bP0, kB2);
    BARX(); LGKM0(); __builtin_amdgcn_s_setprio(1);
    MMA8(af1, bf0, 4, 0) __builtin_amdgcn_s_setprio(0); BARX();
    // ph4
    STG(24576, bP1, kB2);
    VMC4();
    BARX(); __builtin_amdgcn_s_setprio(1);
    MMA8(af1, bf1, 4, 2) __builtin_amdgcn_s_setprio(0); BARX();
    // ph5
    READ_AF0(32768) READ_BF0(49152)
    STG(0, aP0, kB2);
    BARX(); LGKM0(); __builtin_amdgcn_s_setprio(1);
    MMA8(af0, bf0, 0, 0) __builtin_amdgcn_s_setprio(0); BARX();
    // ph6
    READ_BF1(49152)
    STG(8192, aP1, kB2);
    BARX(); LGKM0(); __builtin_amdgcn_s_setprio(1);
    MMA8(af0, bf1, 0, 2) __builtin_amdgcn_s_setprio(0); BARX();
    // ph7
    READ_AF1(32768)
    STG(49152, bP0, kB3);
    BARX(); LGKM0(); __builtin_amdgcn_s_setprio(1);
    MMA8(af1, bf0, 4, 0) __builtin_amdgcn_s_setprio(0); BARX();
    // ph8
    STG(57344, bP1, kB3);
    VMC4();
    BARX(); __builtin_amdgcn_s_setprio(1);
    MMA8(af1, bf1, 4, 2) __builtin_amdgcn_s_setprio(0); BARX();
  }

  // tail: tiles 10 (buf0) and 11 (buf1); only A(11) remains to stage (k=704).
  // ph1
  READ_AF0(0) READ_BF0(16384)
  STG(32768, aP0, 704);
  BARX(); LGKM0(); __builtin_amdgcn_s_setprio(1);
  MMA8(af0, bf0, 0, 0) __builtin_amdgcn_s_setprio(0); BARX();
  // ph2
  READ_BF1(16384)
  STG(40960, aP1, 704);
  BARX(); LGKM0(); __builtin_amdgcn_s_setprio(1);
  MMA8(af0, bf1, 0, 2) __builtin_amdgcn_s_setprio(0); BARX();
  // ph3
  READ_AF1(0)
  BARX(); LGKM0(); __builtin_amdgcn_s_setprio(1);
  MMA8(af1, bf0, 4, 0) __builtin_amdgcn_s_setprio(0); BARX();
  // ph4
  VMC0();
  BARX(); __builtin_amdgcn_s_setprio(1);
  MMA8(af1, bf1, 4, 2) __builtin_amdgcn_s_setprio(0); BARX();
  // ph5
  READ_AF0(32768) READ_BF0(49152)
  BARX(); LGKM0(); __builtin_amdgcn_s_setprio(1);
  MMA8(af0, bf0, 0, 0) __builtin_amdgcn_s_setprio(0); BARX();
  // ph6
  READ_BF1(49152)
  BARX(); LGKM0(); __builtin_amdgcn_s_setprio(1);
  MMA8(af0, bf1, 0, 2) __builtin_amdgcn_s_setprio(0); BARX();
  // ph7
  READ_AF1(32768)
  BARX(); LGKM0(); __builtin_amdgcn_s_setprio(1);
  MMA8(af1, bf0, 4, 0) __builtin_amdgcn_s_setprio(0); BARX();
  // ph8
  __builtin_amdgcn_s_setprio(1);
  MMA8(af1, bf1, 4, 2) __builtin_amdgcn_s_setprio(0);

#undef STG
#undef READ_AF0
#undef READ_AF1
#undef READ_BF0
#undef READ_BF1
#undef MMA8
}

// ---- z = A @ B^T (NT, ld=768): 256x256 tiles, grid (M/256, 3) ----
__global__ __launch_bounds__(512, 2) void gemm_nt_256(const bf16* __restrict__ A,
                                                      const bf16* __restrict__ B,
                                                      bf16* __restrict__ D) {
  __shared__ __align__(16) short sh[65536];
  const int tid = threadIdx.x;
  const int wave = tid >> 6, lane = tid & 63;
  const int lr = lane & 15, quad = lane >> 4;
  const int wm = (wave >> 2) * 128, wn = (wave & 3) * 64;
  const int mblk = blockIdx.x * 256, nblk = blockIdx.y * 256;
  f32x4 acc[8][4] = {};
  core256((const short*)A + (long)mblk * DIM, (const short*)B + (long)nblk * DIM,
          sh, acc, wm, wn, lr, quad, tid);
#pragma unroll
  for (int fi = 0; fi < 8; ++fi)
#pragma unroll
    for (int fj = 0; fj < 4; ++fj)
#pragma unroll
      for (int r = 0; r < 4; ++r)
        D[(long)(mblk + wm + fi * 16 + quad * 4 + r) * DIM +
          nblk + wn + fj * 16 + lr] = __float2bfloat16(acc[fi][fj][r]);
}

// ---- pass1: l[q] += sum_k exp(score[q,k]); no E store. ----
// 1D grid nb*64 blocks, XCD-remapped (each XCD owns one batch's tiles).
__global__ __launch_bounds__(512, 2) void gemm_pass1(const bf16* __restrict__ z,
                                                     const bf16* __restrict__ x,
                                                     const float* __restrict__ betas,
                                                     float* __restrict__ l_out,
                                                     int b0) {
  __shared__ __align__(16) short sh[65536];
  const int nwg = (int)gridDim.x;
  const int cpx = nwg >> 3;  // nwg is a multiple of 8 (nb*64)
  const int bid = (blockIdx.x & 7) * cpx + (blockIdx.x >> 3);
  const int lb = bid >> 6, rb = bid & 63;
  const int mblk = (rb >> 3) * 256, nblk = (rb & 7) * 256;
  const int b = b0 + lb;
  const int tid = threadIdx.x;
  const int wave = tid >> 6, lane = tid & 63;
  const int lr = lane & 15, quad = lane >> 4;
  const int wm = (wave >> 2) * 128, wn = (wave & 3) * 64;
  f32x4 acc[8][4] = {};
  core256((const short*)z + (long)lb * S * DIM + (long)mblk * DIM,
          (const short*)x + (long)b * S * DIM + (long)nblk * DIM,
          sh, acc, wm, wn, lr, quad, tid);
  float bet[4];
#pragma unroll
  for (int fj = 0; fj < 4; ++fj)
    bet[fj] = betas[b * S + nblk + wn + fj * 16 + lr];
  float* lrow = l_out + b * S;
#pragma unroll
  for (int fi = 0; fi < 8; ++fi) {
#pragma unroll
    for (int r = 0; r < 4; ++r) {
      const int q = mblk + wm + fi * 16 + quad * 4 + r;
      float s = 0.f;
#pragma unroll
      for (int fj = 0; fj < 4; ++fj)
        s += __expf(fminf(acc[fi][fj][r] * INV_SCALE + bet[fj], 60.f));
      s += __shfl_xor(s, 1, 64);
      s += __shfl_xor(s, 2, 64);
      s += __shfl_xor(s, 4, 64);
      s += __shfl_xor(s, 8, 64);
      if (lr == 0) atomicAdd(&lrow[q], s);
    }
  }
}

// ---- pass2: c[b,k] += (1/S) sum_q exp(score[q,k])/l[q]; recompute GEMM,
// column-reduce in-register: quad shfl (xor 16,32) -> wave-pair LDS -> one
// atomic per (block,k). E never materialized. ----
__global__ __launch_bounds__(512, 2) void gemm_pass2(const bf16* __restrict__ z,
                                                     const bf16* __restrict__ x,
                                                     const float* __restrict__ betas,
                                                     const float* __restrict__ l,
                                                     float* __restrict__ c,
                                                     int b0) {
  __shared__ __align__(16) short sh[65536];
  const int nwg = (int)gridDim.x;
  const int cpx = nwg >> 3;
  const int bid = (blockIdx.x & 7) * cpx + (blockIdx.x >> 3);
  const int lb = bid >> 6, rb = bid & 63;
  const int mblk = (rb >> 3) * 256, nblk = (rb & 7) * 256;
  const int b = b0 + lb;
  const int tid = threadIdx.x;
  const int wave = tid >> 6, lane = tid & 63;
  const int lr = lane & 15, quad = lane >> 4;
  const int wm = (wave >> 2) * 128, wn = (wave & 3) * 64;
  f32x4 acc[8][4] = {};
  core256((const short*)z + (long)lb * S * DIM + (long)mblk * DIM,
          (const short*)x + (long)b * S * DIM + (long)nblk * DIM,
          sh, acc, wm, wn, lr, quad, tid);
  // stage 1/l for the block's 256 q-rows into LDS (sh is free post-core256)
  float* lds_rq = (float*)sh;          // [256]
  float* cred = (float*)sh + 256;      // [4 waves][4 fj][16 lr]
  if (tid < 256) {
    const float lv = l[b * S + mblk + tid];
    lds_rq[tid] = lv > 0.f ? 1.0f / lv : 0.f;
  }
  float bet[4];
#pragma unroll
  for (int fj = 0; fj < 4; ++fj)
    bet[fj] = betas[b * S + nblk + wn + fj * 16 + lr];
  __syncthreads();
  float csum[4] = {};
#pragma unroll
  for (int fi = 0; fi < 8; ++fi) {
#pragma unroll
    for (int r = 0; r < 4; ++r) {
      const float rqv = lds_rq[wm + fi * 16 + quad * 4 + r];
#pragma unroll
      for (int fj = 0; fj < 4; ++fj)
        csum[fj] += __expf(fminf(acc[fi][fj][r] * INV_SCALE + bet[fj], 60.f)) * rqv;
    }
  }
#pragma unroll
  for (int fj = 0; fj < 4; ++fj) {
    csum[fj] += __shfl_xor(csum[fj], 16, 64);
    csum[fj] += __shfl_xor(csum[fj], 32, 64);
  }
  if (wave >= 4 && quad == 0) {
#pragma unroll
    for (int fj = 0; fj < 4; ++fj)
      cred[((wave & 3) * 4 + fj) * 16 + lr] = csum[fj];
  }
  __syncthreads();
  if (wave < 4 && quad == 0) {
#pragma unroll
    for (int fj = 0; fj < 4; ++fj)
      atomicAdd(&c[b * S + nblk + wn + fj * 16 + lr],
                (csum[fj] + cred[(wave * 4 + fj) * 16 + lr]) * (1.0f / 2048.0f));
  }
}

// ---- y[b,i] = sum_k c[b,k]*x[b,k,i]; grid (3, 16, 8), k-chunk 128 ----
__global__ __launch_bounds__(256) void y_kernel(const bf16* __restrict__ x,
                                                const float* __restrict__ c,
                                                float* __restrict__ y) {
  const int b = blockIdx.z;
  const int i = blockIdx.x * 256 + threadIdx.x;
  const int kstart = blockIdx.y * 128;
  const bf16* xb = x + (long)(b * S + kstart) * DIM + i;
  const float* cb = c + b * S + kstart;
  float acc = 0.f;
  for (int k = 0; k < 128; ++k)
    acc += cb[k] * __bfloat162float(xb[(long)k * DIM]);
  atomicAdd(&y[b * DIM + i], acc);
}

// ---- out[b,o] = y_b . Wv[o,:] + bv[o] (raw Wv/bv, dtype per flag) ----
// grid 1536 x 256: one wave per (b,o) row, vectorized.
__global__ __launch_bounds__(256) void out_kernel(const float* __restrict__ y,
                                                  const void* __restrict__ Wv_raw,
                                                  const void* __restrict__ bv_raw,
                                                  void* __restrict__ out,
                                                  const int* __restrict__ flag) {
  const int wave = threadIdx.x >> 6, lane = threadIdx.x & 63;
  const int w = blockIdx.x * 4 + wave;  // [0, 6144)
  const int b = w / DIM, o = w % DIM;
  const int f = *flag;
  const float4* y4 = (const float4*)(y + (long)b * DIM);
  float s = 0.f;
  if (f) {
    const float4* wr = (const float4*)((const float*)Wv_raw + (long)o * DIM);
#pragma unroll
    for (int it = 0; it < 3; ++it) {
      const int idx = it * 64 + lane;
      const float4 a = y4[idx], wv = wr[idx];
      s += a.x * wv.x + a.y * wv.y + a.z * wv.z + a.w * wv.w;
    }
  } else {
    const short4v* wr = (const short4v*)((const short*)Wv_raw + (long)o * DIM);
#pragma unroll
    for (int it = 0; it < 3; ++it) {
      const int idx = it * 64 + lane;
      const float4 a = y4[idx];
      const short4v wv = wr[idx];
      s += a.x * b2f(wv.x) + a.y * b2f(wv.y) + a.z * b2f(wv.z) + a.w * b2f(wv.w);
    }
  }
#pragma unroll
  for (int off = 1; off < 64; off <<= 1) s += __shfl_xor(s, off, 64);
  if (lane == 0) {
    const float bias = f ? ((const float*)bv_raw)[o] : b2f(((const short*)bv_raw)[o]);
    const float v = s + bias;
    if (f) ((float*)out)[b * DIM + o] = v;
    else ((bf16*)out)[b * DIM + o] = __float2bfloat16(v);
  }
}

extern "C" void kernel_launch(void* const* d_in, const int* in_sizes, int n_in,
                              void* d_out, int out_size, void* d_ws, size_t ws_size,
                              hipStream_t stream) {
  const void* x_raw = d_in[0];
  const int* mask = (const int*)d_in[1];
  const void* Wq_raw = d_in[2];
  const void* bq_raw = d_in[3];
  const void* Wk_raw = d_in[4];
  // d_in[5] = bk: provably cancels out of the computation.
  const void* Wv_raw = d_in[6];
  const void* bv_raw = d_in[7];

  char* ws = (char*)d_ws;
  bf16* xb = (bf16*)(ws);                   //          0 .. 25,165,824
  bf16* WqT = (bf16*)(ws + 25165824);       // 1,179,648 B
  bf16* WkT = (bf16*)(ws + 26345472);       // 1,179,648 B
  bf16* Mt = (bf16*)(ws + 27525120);        // 1,179,648 B  Mt[j,i]=M[i,j]
  float* betas = (float*)(ws + 28704768);   //    65,536 B
  // ---- zeroed region starts here ----
  float* bvec = (float*)(ws + 28770304);    //     3,072 B
  float* l = (float*)(ws + 28773376);       //    65,536 B
  float* c = (float*)(ws + 28838912);       //    65,536 B
  float* y = (float*)(ws + 28904448);       //    24,576 B
  int* flag = (int*)(ws + 28929024);        //        64 B
  bf16* z = (bf16*)(ws + 28929088);         // nb * 3,145,728 B

  const size_t fixed = 28929088;
  const size_t zb = 3145728;  // per-batch z bytes (E eliminated)
  int nb = 1;
  if (ws_size >= fixed + 8 * zb) nb = 8;
  else if (ws_size >= fixed + 4 * zb) nb = 4;
  else if (ws_size >= fixed + 2 * zb) nb = 2;
  const int rounds = BATCH / nb;

  // zero bvec, l, c, y, flag (contiguous)
  (void)hipMemsetAsync(bvec, 0, 3072 + 65536 + 65536 + 24576 + 64, stream);

  prep_kernel<<<294, 256, 0, stream>>>(x_raw, Wq_raw, Wk_raw, bq_raw, WqT, WkT,
                                       bvec, flag);
  mt_convert<<<4132, 256, 0, stream>>>(WkT, WqT, Mt, x_raw, mask, bvec, xb,
                                       betas, flag);

  for (int r = 0; r < rounds; ++r) {
    const int b0 = r * nb;
    // z[lb*S+q, :] = x[b0+lb, q, :] @ M
    gemm_nt_256<<<dim3(nb * 8, 3), 512, 0, stream>>>(
        xb + (long)b0 * S * DIM, Mt, z);
    gemm_pass1<<<nb * 64, 512, 0, stream>>>(z, xb, betas, l, b0);
    gemm_pass2<<<nb * 64, 512, 0, stream>>>(z, xb, betas, l, c, b0);
  }

  y_kernel<<<dim3(3, 16, 8), 256, 0, stream>>>(xb, c, y);
  out_kernel<<<1536, 256, 0, stream>>>(y, Wv_raw, bv_raw, d_out, flag);
}